// Round 7
// baseline (506.259 us; speedup 1.0000x reference)
//
#include <hip/hip_runtime.h>

#define TPB 256

// ---------------------------------------------------------------------------
// B=8, H=W=256, Cin=Cout=8, N=511 (=2H-1), crop offset 127.
// f16x3 split-precision MFMA pipeline (v_mfma_f32_32x32x16_f16):
//   complex values as 4 f16 planes (rh, rl, ih, il), x = hi+lo exact;
//   a*b ~= ah*bh + ah*bl + al*bh (al*bl ~2^-22 dropped).
//
// mgemm: 128x64 block, 4 waves (2m x 2n), wave = 64x32 = 2x1 c-tiles of 32x32.
// Double-buffered LDS data staging, ONE barrier per k-step, data global loads
// one step ahead. Table operand direct-from-global (fragment-native, L2).
// ---------------------------------------------------------------------------

typedef _Float16 half8  __attribute__((ext_vector_type(8)));
typedef float    floatx16 __attribute__((ext_vector_type(16)));
typedef unsigned int uintx4 __attribute__((ext_vector_type(4)));

__device__ __forceinline__ void split16(float v, _Float16& h, _Float16& l) {
    h = (_Float16)v;
    l = (_Float16)(v - (float)h);
}

// ---------------------------------------------------------------------------
// Fragment-native tables.
// Atab: M=512 (k1), K=256 (n): exp(-2*pi*i*k1*n/511), row 511 = 0. 1MB.
// Ctab: M=256 (p), K=512 (k1): exp(+2*pi*i*k1*(p+127)/511), k=511 -> 0. 1MB.
// Ct2 : N=256 (q), K=256 (k2): exp(+2*pi*i*k2*(q+127)/511). 512KB.
// Element (R,k,plane p) at: ((tile*(K/16)+kcblk)*4+p)*512 + lane*8 + (k&7),
//   tile=R>>5, kcblk=k>>4, lane=(R&31)+32*((k>>3)&1).
// ---------------------------------------------------------------------------
__global__ __launch_bounds__(TPB)
void build_tables_k(_Float16* __restrict__ At, _Float16* __restrict__ Ct,
                    _Float16* __restrict__ C2) {
    int idx = blockIdx.x * TPB + threadIdx.x;   // [0, 40960)
    const float w = (float)(6.28318530717958647692 / 511.0);
    _Float16* T; int R, kc2, K; int mode;
    if (idx < 16384)      { T = At; R = idx >> 5;  kc2 = idx & 31; K = 256; mode = 0; }
    else if (idx < 32768) { int id = idx - 16384; T = Ct; R = id >> 6; kc2 = id & 63; K = 512; mode = 1; }
    else                  { int id = idx - 32768; T = C2; R = id >> 5; kc2 = id & 31; K = 256; mode = 2; }

    half8 vrh, vrl, vih, vil;
    #pragma unroll
    for (int j = 0; j < 8; j++) {
        int k = kc2 * 8 + j;
        float cr = 0.f, ci = 0.f;
        if (mode == 0) {
            if (R < 511) {
                int m = (R * k) % 511;
                float s, c; sincosf(w * (float)m, &s, &c);
                cr = c; ci = -s;
            }
        } else {
            if (!(mode == 1 && k == 511)) {
                int m = (k * (R + 127)) % 511;
                float s, c; sincosf(w * (float)m, &s, &c);
                cr = c; ci = s;
            }
        }
        _Float16 th, tl;
        split16(cr, th, tl); vrh[j] = th; vrl[j] = tl;
        split16(ci, th, tl); vih[j] = th; vil[j] = tl;
    }
    int tile = R >> 5, kcblk = kc2 >> 1, lane = (R & 31) + 32 * (kc2 & 1);
    size_t base = ((size_t)(tile * (K >> 4) + kcblk) * 4) * 512 + lane * 8;
    *(half8*)(T + base)        = vrh;
    *(half8*)(T + base + 512)  = vrl;
    *(half8*)(T + base + 1024) = vih;
    *(half8*)(T + base + 1536) = vil;
}

// ---------------------------------------------------------------------------
// x [b][n][w][i] fp32 -> xTp [z=(b,i)][col=w][kc=n>>3][plane2][8]
// ---------------------------------------------------------------------------
__global__ __launch_bounds__(TPB)
void txp_k(const float* __restrict__ x, _Float16* __restrict__ xT) {
    __shared__ _Float16 L[8][2][32][40];
    const int tid = threadIdx.x;
    const int b = blockIdx.z, n0 = blockIdx.y * 32, w0 = blockIdx.x * 32;
    #pragma unroll
    for (int pp = 0; pp < 4; pp++) {
        int w = tid & 31, n = pp * 8 + (tid >> 5);
        const float4* src = (const float4*)(x + ((size_t)((b * 256 + n0 + n) * 256) + w0 + w) * 8);
        float4 v0 = src[0], v1 = src[1];
        float vv[8] = {v0.x, v0.y, v0.z, v0.w, v1.x, v1.y, v1.z, v1.w};
        #pragma unroll
        for (int ch = 0; ch < 8; ch++) {
            _Float16 h, lo; split16(vv[ch], h, lo);
            L[ch][0][w][n] = h;
            L[ch][1][w][n] = lo;
        }
    }
    __syncthreads();
    #pragma unroll
    for (int t = 0; t < 8; t++) {
        int c = tid + t * 256;          // 2048 chunks: [ch][w][cc][p]
        int p = c & 1, cc = (c >> 1) & 3, w = (c >> 3) & 31, ch = c >> 8;
        uintx4 v = *(const uintx4*)&L[ch][p][w][cc * 8];
        size_t off = ((size_t)(b * 8 + ch)) * 131072 + (size_t)(w0 + w) * 512
                   + (size_t)((n0 >> 3) + cc) * 16 + p * 8;
        *(uintx4*)(xT + off) = v;
    }
}

// ---------------------------------------------------------------------------
// Hermitian-symmetrized kernel, fp32: KeR/KeI [io64][k2*512 + k1]
// Ke = 0.5*w(k2)*(Kc(k1,k2) + conj(Kc(-k1,-k2))), w(0)=1 else 2.
// ---------------------------------------------------------------------------
__global__ __launch_bounds__(TPB)
void ksym_k(const float* __restrict__ Kr, const float* __restrict__ Ki,
            float* __restrict__ KeR, float* __restrict__ KeI) {
    __shared__ float LR[64][65];
    __shared__ float LI[64][65];
    const int tid = threadIdx.x;
    const int k2  = blockIdx.x >> 3;
    const int k1g = (blockIdx.x & 7) * 64;
    const int k2m = (k2 == 0) ? 0 : 511 - k2;
    const float sc = (k2 == 0) ? 0.5f : 1.0f;
    #pragma unroll
    for (int t = 0; t < 4; t++) {
        int idx = tid + t * 256;
        int j = idx & 15, k1l = idx >> 4;
        int k1 = k1g + k1l;
        float4 rs = {0,0,0,0}, rm = {0,0,0,0}, is = {0,0,0,0}, im = {0,0,0,0};
        if (k1 < 511) {
            int k1m = (k1 == 0) ? 0 : 511 - k1;
            size_t so = ((size_t)(k1  * 511 + k2 )) * 64 + j * 4;
            size_t mo = ((size_t)(k1m * 511 + k2m)) * 64 + j * 4;
            rs = *(const float4*)(Kr + so);
            rm = *(const float4*)(Kr + mo);
            is = *(const float4*)(Ki + so);
            im = *(const float4*)(Ki + mo);
        }
        LR[j*4+0][k1l] = sc * (rs.x + rm.x);
        LR[j*4+1][k1l] = sc * (rs.y + rm.y);
        LR[j*4+2][k1l] = sc * (rs.z + rm.z);
        LR[j*4+3][k1l] = sc * (rs.w + rm.w);
        LI[j*4+0][k1l] = sc * (is.x - im.x);
        LI[j*4+1][k1l] = sc * (is.y - im.y);
        LI[j*4+2][k1l] = sc * (is.z - im.z);
        LI[j*4+3][k1l] = sc * (is.w - im.w);
    }
    __syncthreads();
    const size_t ob = (size_t)k2 * 512 + k1g;
    #pragma unroll
    for (int t = 0; t < 4; t++) {
        int idx = tid + t * 256;
        int io = idx >> 4, fq = idx & 15;
        float4 vr = make_float4(LR[io][fq*4], LR[io][fq*4+1], LR[io][fq*4+2], LR[io][fq*4+3]);
        float4 vi = make_float4(LI[io][fq*4], LI[io][fq*4+1], LI[io][fq*4+2], LI[io][fq*4+3]);
        *(float4*)(KeR + (size_t)io * 131072 + ob + fq * 4) = vr;
        *(float4*)(KeI + (size_t)io * 131072 + ob + fq * 4) = vi;
    }
}

// ---------------------------------------------------------------------------
// Split-f16 MFMA GEMM. Block 128x64, 4 waves (2m x 2n), wave = 64x32 output
// (2 mt-tiles of 32x32). Double-buffered LDS data staging, one barrier/step.
// NPD: data planes (4 complex / 2 real). TBA: table is A (data is B).
// DREAL: fp32 Re-only output.
// ---------------------------------------------------------------------------
template<int NPD, bool TBA, bool DREAL>
__global__ __launch_bounds__(TPB, 3)
void mgemm_k(int K, const _Float16* __restrict__ Tf,
             const _Float16* __restrict__ Dd, long sDz,
             _Float16* __restrict__ Out, long sOz, int OutKc,
             float* __restrict__ Of, long sOfz, int OfN)
{
    constexpr int SLOTS = NPD * 2;            // 16B slots per col per step
    constexpr int DE  = TBA ? 64 : 128;       // data-side extent in block
    constexpr int DT  = TBA ? 1 : 2;          // data tiles per wave
    constexpr int TT  = TBA ? 2 : 1;          // table tiles per wave
    constexpr int CPT = DE * SLOTS / TPB;     // staged chunks per thread
    constexpr int BUF = DE * SLOTS * 8;       // halfs per LDS buffer
    __shared__ _Float16 sm[2 * BUF];

    const int tid = threadIdx.x;
    const int bm = blockIdx.y * 128, bn = blockIdx.x * 64;
    const int z = blockIdx.z;
    const _Float16* D = Dd + (size_t)z * sDz;

    const int l  = tid & 63;
    const int wv = tid >> 6;
    const int lr = l & 31, lg = l >> 5;
    const int wm = (wv >> 1) * 64, wn = (wv & 1) * 32;
    const int Kc16 = K >> 4;

    // table-side tile bases
    const int tb = (TBA ? bm + wm : bn + wn);
    int tTB[TT];
    #pragma unroll
    for (int t = 0; t < TT; t++) tTB[t] = ((tb + t * 32) >> 5) * Kc16;

    // data-side fragment LDS offsets
    const int db = (TBA ? wn : wm);
    int dOff[DT][NPD];
    #pragma unroll
    for (int t = 0; t < DT; t++) {
        int cl = db + t * 32 + lr;
        int sw = cl & (SLOTS - 1);
        #pragma unroll
        for (int p = 0; p < NPD; p++)
            dOff[t][p] = cl * (NPD * 16) + (((p * 2 + lg) ^ sw) * 8);
    }

    // staging descriptors
    const int bSide = (TBA ? bn : bm);
    const _Float16* gP[CPT];
    int lO[CPT];
    #pragma unroll
    for (int j = 0; j < CPT; j++) {
        int cid = tid + j * TPB;
        int col = cid / SLOTS;
        int inner = cid & (SLOTS - 1);
        int p = inner & (NPD - 1);
        int h = inner / NPD;
        gP[j] = D + ((size_t)(bSide + col) * (K >> 3) + h) * (NPD * 8) + p * 8;
        lO[j] = col * (NPD * 16) + (((p * 2 + h) ^ (col & (SLOTS - 1))) * 8);
    }

    floatx16 accR[2], accI[2];
    #pragma unroll
    for (int i = 0; i < 2; i++)
        #pragma unroll
        for (int r = 0; r < 16; r++) { accR[i][r] = 0.f; accI[i][r] = 0.f; }

    // prologue: stage step 0, prefetch step 1
    uintx4 st[CPT];
    #pragma unroll
    for (int j = 0; j < CPT; j++) { st[j] = *(const uintx4*)gP[j]; gP[j] += NPD * 16; }
    #pragma unroll
    for (int j = 0; j < CPT; j++) *(uintx4*)(sm + lO[j]) = st[j];
    #pragma unroll
    for (int j = 0; j < CPT; j++) { st[j] = *(const uintx4*)gP[j]; gP[j] += NPD * 16; }
    __syncthreads();

    const int NT = K >> 4;
    for (int t = 0; t < NT; t++) {
        const int cur = t & 1;
        const _Float16* smc = sm + cur * BUF;

        // table fragments (global, L2-cached, coalesced 1KB/wave each)
        half8 tf[TT][4];
        #pragma unroll
        for (int tt = 0; tt < TT; tt++)
            #pragma unroll
            for (int p = 0; p < 4; p++)
                tf[tt][p] = *(const half8*)(Tf + ((size_t)(tTB[tt] + t) * 4 + p) * 512 + l * 8);
        // data fragments (LDS)
        half8 df[DT][NPD];
        #pragma unroll
        for (int dt = 0; dt < DT; dt++)
            #pragma unroll
            for (int p = 0; p < NPD; p++)
                df[dt][p] = *(const half8*)(smc + dOff[dt][p]);

        if constexpr (TBA && NPD == 4 && !DREAL) {
            // complex x complex: A = table, B = data (S2/S4)
            half8 na[2][2];
            #pragma unroll
            for (int mt = 0; mt < 2; mt++)
                #pragma unroll
                for (int p = 0; p < 2; p++) {
                    uintx4 u = __builtin_bit_cast(uintx4, tf[mt][2 + p]);
                    u ^= 0x80008000u;
                    na[mt][p] = __builtin_bit_cast(half8, u);
                }
            #pragma unroll
            for (int mt = 0; mt < 2; mt++) {
                accR[mt] = __builtin_amdgcn_mfma_f32_32x32x16_f16(tf[mt][0], df[0][0], accR[mt], 0,0,0);
                accR[mt] = __builtin_amdgcn_mfma_f32_32x32x16_f16(tf[mt][0], df[0][1], accR[mt], 0,0,0);
                accR[mt] = __builtin_amdgcn_mfma_f32_32x32x16_f16(tf[mt][1], df[0][0], accR[mt], 0,0,0);
                accR[mt] = __builtin_amdgcn_mfma_f32_32x32x16_f16(na[mt][0], df[0][2], accR[mt], 0,0,0);
                accR[mt] = __builtin_amdgcn_mfma_f32_32x32x16_f16(na[mt][0], df[0][3], accR[mt], 0,0,0);
                accR[mt] = __builtin_amdgcn_mfma_f32_32x32x16_f16(na[mt][1], df[0][2], accR[mt], 0,0,0);
                accI[mt] = __builtin_amdgcn_mfma_f32_32x32x16_f16(tf[mt][0], df[0][2], accI[mt], 0,0,0);
                accI[mt] = __builtin_amdgcn_mfma_f32_32x32x16_f16(tf[mt][0], df[0][3], accI[mt], 0,0,0);
                accI[mt] = __builtin_amdgcn_mfma_f32_32x32x16_f16(tf[mt][1], df[0][2], accI[mt], 0,0,0);
                accI[mt] = __builtin_amdgcn_mfma_f32_32x32x16_f16(tf[mt][2], df[0][0], accI[mt], 0,0,0);
                accI[mt] = __builtin_amdgcn_mfma_f32_32x32x16_f16(tf[mt][2], df[0][1], accI[mt], 0,0,0);
                accI[mt] = __builtin_amdgcn_mfma_f32_32x32x16_f16(tf[mt][3], df[0][0], accI[mt], 0,0,0);
            }
        } else if constexpr (TBA && NPD == 2) {
            // S1: complex table x real data
            #pragma unroll
            for (int mt = 0; mt < 2; mt++) {
                accR[mt] = __builtin_amdgcn_mfma_f32_32x32x16_f16(tf[mt][0], df[0][0], accR[mt], 0,0,0);
                accR[mt] = __builtin_amdgcn_mfma_f32_32x32x16_f16(tf[mt][0], df[0][1], accR[mt], 0,0,0);
                accR[mt] = __builtin_amdgcn_mfma_f32_32x32x16_f16(tf[mt][1], df[0][0], accR[mt], 0,0,0);
                accI[mt] = __builtin_amdgcn_mfma_f32_32x32x16_f16(tf[mt][2], df[0][0], accI[mt], 0,0,0);
                accI[mt] = __builtin_amdgcn_mfma_f32_32x32x16_f16(tf[mt][2], df[0][1], accI[mt], 0,0,0);
                accI[mt] = __builtin_amdgcn_mfma_f32_32x32x16_f16(tf[mt][3], df[0][0], accI[mt], 0,0,0);
            }
        } else {
            // S5: A = data (LDS complex), B = table, Re-only
            half8 nd[2][2];
            #pragma unroll
            for (int mt = 0; mt < 2; mt++)
                #pragma unroll
                for (int p = 0; p < 2; p++) {
                    uintx4 u = __builtin_bit_cast(uintx4, df[mt][2 + p]);
                    u ^= 0x80008000u;
                    nd[mt][p] = __builtin_bit_cast(half8, u);
                }
            #pragma unroll
            for (int mt = 0; mt < 2; mt++) {
                accR[mt] = __builtin_amdgcn_mfma_f32_32x32x16_f16(df[mt][0], tf[0][0], accR[mt], 0,0,0);
                accR[mt] = __builtin_amdgcn_mfma_f32_32x32x16_f16(df[mt][0], tf[0][1], accR[mt], 0,0,0);
                accR[mt] = __builtin_amdgcn_mfma_f32_32x32x16_f16(df[mt][1], tf[0][0], accR[mt], 0,0,0);
                accR[mt] = __builtin_amdgcn_mfma_f32_32x32x16_f16(nd[mt][0], tf[0][2], accR[mt], 0,0,0);
                accR[mt] = __builtin_amdgcn_mfma_f32_32x32x16_f16(nd[mt][0], tf[0][3], accR[mt], 0,0,0);
                accR[mt] = __builtin_amdgcn_mfma_f32_32x32x16_f16(nd[mt][1], tf[0][2], accR[mt], 0,0,0);
            }
        }

        // stage next step into the other buffer; keep loads one step ahead
        if (t + 1 < NT) {
            _Float16* smn = sm + (cur ^ 1) * BUF;
            #pragma unroll
            for (int j = 0; j < CPT; j++) *(uintx4*)(smn + lO[j]) = st[j];
            if (t + 2 < NT) {
                #pragma unroll
                for (int j = 0; j < CPT; j++) { st[j] = *(const uintx4*)gP[j]; gP[j] += NPD * 16; }
            }
            __syncthreads();
        }
    }

    // epilogue: C/D layout col = lane&31, row = (r&3) + 8*(r>>2) + 4*lg
    if constexpr (DREAL) {
        float* Dv = Of + (size_t)z * sOfz;
        #pragma unroll
        for (int mt = 0; mt < 2; mt++)
            #pragma unroll
            for (int r = 0; r < 16; r++) {
                int row = bm + wm + mt * 32 + (r & 3) + 8 * (r >> 2) + 4 * lg;
                int col = bn + wn + lr;
                Dv[(size_t)row * OfN + col] = accR[mt][r];
            }
    } else {
        _Float16* O = Out + (size_t)z * sOz;
        #pragma unroll
        for (int mt = 0; mt < 2; mt++)
            #pragma unroll
            for (int r = 0; r < 16; r++) {
                int row = bm + wm + mt * 32 + (r & 3) + 8 * (r >> 2) + 4 * lg;
                int col = bn + wn + lr;
                size_t base = ((size_t)row * OutKc + (col >> 3)) * 32 + (col & 7);
                _Float16 h, lo;
                split16(accR[mt][r], h, lo);
                O[base]      = h;
                O[base + 8]  = lo;
                split16(accI[mt][r], h, lo);
                O[base + 16] = h;
                O[base + 24] = lo;
            }
    }
}

// ---------------------------------------------------------------------------
// Channel mix on F2T (interleaved layout), image-tiled by 4 to reuse Ke.
// ---------------------------------------------------------------------------
__global__ __launch_bounds__(TPB)
void einsum_k(_Float16* __restrict__ F, const float* __restrict__ KeR,
              const float* __restrict__ KeI, int g)
{
    const int pt = blockIdx.x * TPB + threadIdx.x;   // k2*512 + k1
    const int k2 = pt >> 9, k1 = pt & 511;
    const size_t fo = ((size_t)(k2 * 64 + (k1 >> 3))) * 32 + (k1 & 7);

    for (int b0 = 0; b0 < g; b0 += 4) {
        const int bt = (g - b0 < 4) ? (g - b0) : 4;
        float xr[4][8], xi[4][8];
        #pragma unroll
        for (int bb = 0; bb < 4; bb++) {
            if (bb >= bt) break;
            #pragma unroll
            for (int i = 0; i < 8; i++) {
                const _Float16* P = F + ((size_t)((b0 + bb) * 8 + i)) * 524288 + fo;
                xr[bb][i] = (float)P[0]  + (float)P[8];
                xi[bb][i] = (float)P[16] + (float)P[24];
            }
        }
        #pragma unroll
        for (int o = 0; o < 8; o++) {
            float ar[4] = {0.f,0.f,0.f,0.f}, ai[4] = {0.f,0.f,0.f,0.f};
            #pragma unroll
            for (int i = 0; i < 8; i++) {
                float kr = KeR[(size_t)(i * 8 + o) * 131072 + pt];
                float ki = KeI[(size_t)(i * 8 + o) * 131072 + pt];
                #pragma unroll
                for (int bb = 0; bb < 4; bb++) {
                    ar[bb] = fmaf(xr[bb][i], kr, ar[bb]);
                    ar[bb] = fmaf(-xi[bb][i], ki, ar[bb]);
                    ai[bb] = fmaf(xr[bb][i], ki, ai[bb]);
                    ai[bb] = fmaf(xi[bb][i], kr, ai[bb]);
                }
            }
            #pragma unroll
            for (int bb = 0; bb < 4; bb++) {
                if (bb >= bt) break;
                _Float16* Q = F + ((size_t)((b0 + bb) * 8 + o)) * 524288 + fo;
                _Float16 h, lo;
                split16(ar[bb], h, lo); Q[0]  = h; Q[8]  = lo;
                split16(ai[bb], h, lo); Q[16] = h; Q[24] = lo;
            }
        }
    }
}

// ---------------------------------------------------------------------------
// out[b][p][q][o] = Dq[(bl*8+o)][p*256+q] / 511^2 + bias[o]
// ---------------------------------------------------------------------------
__global__ __launch_bounds__(TPB)
void tout_k(const float* __restrict__ Dq, const float* __restrict__ bias,
            float* __restrict__ out, int b0)
{
    int idx = blockIdx.x * TPB + threadIdx.x;
    int o = idx & 7, q = (idx >> 3) & 255, p = (idx >> 11) & 255, bl = idx >> 19;
    float v = Dq[(size_t)(bl * 8 + o) * 65536 + p * 256 + q];
    out[(size_t)(b0 + bl) * 524288 + (size_t)(idx & 524287)] = v * (1.f / 261121.f) + bias[o];
}

// ---------------------------------------------------------------------------

extern "C" void kernel_launch(void* const* d_in, const int* in_sizes, int n_in,
                              void* d_out, int out_size, void* d_ws, size_t ws_size,
                              hipStream_t stream) {
    const float* x    = (const float*)d_in[0];
    const float* Kr   = (const float*)d_in[1];
    const float* Ki   = Kr + 16711744;          // 511*511*64
    const float* bias = (const float*)d_in[2];
    float* out = (float*)d_out;
    char* ws = (char*)d_ws;

    _Float16* AtabF = (_Float16*)(ws + 0);           //  1,048,576
    _Float16* CtabF = (_Float16*)(ws + 1048576);     //  1,048,576
    _Float16* Ct2F  = (_Float16*)(ws + 2097152);     //    524,288
    _Float16* xTp   = (_Float16*)(ws + 2621440);     // 16,777,216
    float*    KeR   = (float*)   (ws + 19398656);    // 33,554,432
    float*    KeI   = (float*)   (ws + 52953088);    // 33,554,432
    const size_t fixedEnd = 86507520;

    int g = 1;
    for (int cand = 8; cand >= 1; cand >>= 1) {
        if (fixedEnd + (size_t)cand * 16777216 <= ws_size) { g = cand; break; }
    }
    _Float16* F1  = (_Float16*)(ws + fixedEnd);                        // g*8 MB
    _Float16* F2T = (_Float16*)(ws + fixedEnd + (size_t)g * 8388608);  // g*8 MB
    _Float16* F1b = F1;                 // alias: F1 dead after S2
    float*    Dq  = (float*)F2T;        // alias: F2T dead after S4

    build_tables_k<<<160, TPB, 0, stream>>>(AtabF, CtabF, Ct2F);
    txp_k<<<dim3(8, 8, 8), TPB, 0, stream>>>(x, xTp);
    ksym_k<<<2048, TPB, 0, stream>>>(Kr, Ki, KeR, KeI);

    for (int b0 = 0; b0 < 8; b0 += g) {
        int Z = g * 8;
        // S1: F1[k1][w] (M=512,N=256,K=256), A=Atab, B=xTp (real)
        mgemm_k<2, true, false><<<dim3(4, 4, Z), TPB, 0, stream>>>(
            256, AtabF,
            xTp + (size_t)b0 * 8 * 131072, 131072,
            F1, 524288, 32, nullptr, 0, 0);

        // S2: F2T[k2][k1] (M=256,N=512,K=256), A=Atab(rows 0..255), B=F1
        mgemm_k<4, true, false><<<dim3(8, 2, Z), TPB, 0, stream>>>(
            256, AtabF,
            F1, 524288,
            F2T, 524288, 64, nullptr, 0, 0);

        // S3: channel mix
        einsum_k<<<512, TPB, 0, stream>>>(F2T, KeR, KeI, g);

        // S4: F1'[p][k2] (M=256,N=256,K=512), A=Ctab, B=F2T
        mgemm_k<4, true, false><<<dim3(4, 2, Z), TPB, 0, stream>>>(
            512, CtabF,
            F2T, 524288,
            F1b, 262144, 32, nullptr, 0, 0);

        // S5: Dq[p][q] (M=256,N=256,K=256), A=F1' (data), B=Ct2 table, fp32 Re
        mgemm_k<4, false, true><<<dim3(4, 2, Z), TPB, 0, stream>>>(
            256, Ct2F,
            F1b, 262144,
            nullptr, 0, 0, Dq, 65536, 256);

        // S6: transpose to NHWC + scale + bias
        tout_k<<<g * 2048, TPB, 0, stream>>>(Dq, bias, out, b0);
    }
}

// Round 8
// 474.974 us; speedup vs baseline: 1.0659x; 1.0659x over previous
//
#include <hip/hip_runtime.h>

#define TPB 256

// ---------------------------------------------------------------------------
// B=8, H=W=256, Cin=Cout=8, N=511 (=2H-1), crop offset 127.
// f16x3 split-precision MFMA pipeline (v_mfma_f32_32x32x16_f16):
//   complex values as 4 f16 planes (rh, rl, ih, il), x = hi+lo exact;
//   a*b ~= ah*bh + ah*bl + al*bh (al*bl ~2^-22 dropped).
//
// mgemm v3: block (2*WM)x(2*WN), 4 waves (2x2), wave tile WMxWN.
// Double-buffered LDS data staging, ONE barrier per k-step; data global
// loads one step ahead (register-staged); table fragments direct-from-global
// (fragment-native), reloaded into the same regs AFTER the MFMA block so the
// barrier's vmcnt drain guarantees availability with no extra registers.
// ---------------------------------------------------------------------------

typedef _Float16 half8  __attribute__((ext_vector_type(8)));
typedef float    floatx16 __attribute__((ext_vector_type(16)));
typedef unsigned int uintx4 __attribute__((ext_vector_type(4)));

__device__ __forceinline__ void split16(float v, _Float16& h, _Float16& l) {
    h = (_Float16)v;
    l = (_Float16)(v - (float)h);
}

__device__ __forceinline__ half8 neg8(half8 v) {
    uintx4 u = __builtin_bit_cast(uintx4, v);
    u ^= 0x80008000u;
    return __builtin_bit_cast(half8, u);
}

// ---------------------------------------------------------------------------
// Fragment-native tables.
// Atab: M=512 (k1), K=256 (n): exp(-2*pi*i*k1*n/511), row 511 = 0. 1MB.
// Ctab: M=256 (p), K=512 (k1): exp(+2*pi*i*k1*(p+127)/511), k=511 -> 0. 1MB.
// Ct2 : N=256 (q), K=256 (k2): exp(+2*pi*i*k2*(q+127)/511). 512KB.
// Element (R,k,plane p) at: ((tile*(K/16)+kcblk)*4+p)*512 + lane*8 + (k&7),
//   tile=R>>5, kcblk=k>>4, lane=(R&31)+32*((k>>3)&1).
// ---------------------------------------------------------------------------
__global__ __launch_bounds__(TPB)
void build_tables_k(_Float16* __restrict__ At, _Float16* __restrict__ Ct,
                    _Float16* __restrict__ C2) {
    int idx = blockIdx.x * TPB + threadIdx.x;   // [0, 40960)
    const float w = (float)(6.28318530717958647692 / 511.0);
    _Float16* T; int R, kc2, K; int mode;
    if (idx < 16384)      { T = At; R = idx >> 5;  kc2 = idx & 31; K = 256; mode = 0; }
    else if (idx < 32768) { int id = idx - 16384; T = Ct; R = id >> 6; kc2 = id & 63; K = 512; mode = 1; }
    else                  { int id = idx - 32768; T = C2; R = id >> 5; kc2 = id & 31; K = 256; mode = 2; }

    half8 vrh, vrl, vih, vil;
    #pragma unroll
    for (int j = 0; j < 8; j++) {
        int k = kc2 * 8 + j;
        float cr = 0.f, ci = 0.f;
        if (mode == 0) {
            if (R < 511) {
                int m = (R * k) % 511;
                float s, c; sincosf(w * (float)m, &s, &c);
                cr = c; ci = -s;
            }
        } else {
            if (!(mode == 1 && k == 511)) {
                int m = (k * (R + 127)) % 511;
                float s, c; sincosf(w * (float)m, &s, &c);
                cr = c; ci = s;
            }
        }
        _Float16 th, tl;
        split16(cr, th, tl); vrh[j] = th; vrl[j] = tl;
        split16(ci, th, tl); vih[j] = th; vil[j] = tl;
    }
    int tile = R >> 5, kcblk = kc2 >> 1, lane = (R & 31) + 32 * (kc2 & 1);
    size_t base = ((size_t)(tile * (K >> 4) + kcblk) * 4) * 512 + lane * 8;
    *(half8*)(T + base)        = vrh;
    *(half8*)(T + base + 512)  = vrl;
    *(half8*)(T + base + 1024) = vih;
    *(half8*)(T + base + 1536) = vil;
}

// ---------------------------------------------------------------------------
// x [b][n][w][i] fp32 -> xTp [z=(b,i)][col=w][kc=n>>3][plane2][8]
// ---------------------------------------------------------------------------
__global__ __launch_bounds__(TPB)
void txp_k(const float* __restrict__ x, _Float16* __restrict__ xT) {
    __shared__ _Float16 L[8][2][32][40];
    const int tid = threadIdx.x;
    const int b = blockIdx.z, n0 = blockIdx.y * 32, w0 = blockIdx.x * 32;
    #pragma unroll
    for (int pp = 0; pp < 4; pp++) {
        int w = tid & 31, n = pp * 8 + (tid >> 5);
        const float4* src = (const float4*)(x + ((size_t)((b * 256 + n0 + n) * 256) + w0 + w) * 8);
        float4 v0 = src[0], v1 = src[1];
        float vv[8] = {v0.x, v0.y, v0.z, v0.w, v1.x, v1.y, v1.z, v1.w};
        #pragma unroll
        for (int ch = 0; ch < 8; ch++) {
            _Float16 h, lo; split16(vv[ch], h, lo);
            L[ch][0][w][n] = h;
            L[ch][1][w][n] = lo;
        }
    }
    __syncthreads();
    #pragma unroll
    for (int t = 0; t < 8; t++) {
        int c = tid + t * 256;          // 2048 chunks: [ch][w][cc][p]
        int p = c & 1, cc = (c >> 1) & 3, w = (c >> 3) & 31, ch = c >> 8;
        uintx4 v = *(const uintx4*)&L[ch][p][w][cc * 8];
        size_t off = ((size_t)(b * 8 + ch)) * 131072 + (size_t)(w0 + w) * 512
                   + (size_t)((n0 >> 3) + cc) * 16 + p * 8;
        *(uintx4*)(xT + off) = v;
    }
}

// ---------------------------------------------------------------------------
// Hermitian-symmetrized kernel, fp32: KeR/KeI [io64][k2*512 + k1]
// Ke = 0.5*w(k2)*(Kc(k1,k2) + conj(Kc(-k1,-k2))), w(0)=1 else 2.
// ---------------------------------------------------------------------------
__global__ __launch_bounds__(TPB)
void ksym_k(const float* __restrict__ Kr, const float* __restrict__ Ki,
            float* __restrict__ KeR, float* __restrict__ KeI) {
    __shared__ float LR[64][65];
    __shared__ float LI[64][65];
    const int tid = threadIdx.x;
    const int k2  = blockIdx.x >> 3;
    const int k1g = (blockIdx.x & 7) * 64;
    const int k2m = (k2 == 0) ? 0 : 511 - k2;
    const float sc = (k2 == 0) ? 0.5f : 1.0f;
    #pragma unroll
    for (int t = 0; t < 4; t++) {
        int idx = tid + t * 256;
        int j = idx & 15, k1l = idx >> 4;
        int k1 = k1g + k1l;
        float4 rs = {0,0,0,0}, rm = {0,0,0,0}, is = {0,0,0,0}, im = {0,0,0,0};
        if (k1 < 511) {
            int k1m = (k1 == 0) ? 0 : 511 - k1;
            size_t so = ((size_t)(k1  * 511 + k2 )) * 64 + j * 4;
            size_t mo = ((size_t)(k1m * 511 + k2m)) * 64 + j * 4;
            rs = *(const float4*)(Kr + so);
            rm = *(const float4*)(Kr + mo);
            is = *(const float4*)(Ki + so);
            im = *(const float4*)(Ki + mo);
        }
        LR[j*4+0][k1l] = sc * (rs.x + rm.x);
        LR[j*4+1][k1l] = sc * (rs.y + rm.y);
        LR[j*4+2][k1l] = sc * (rs.z + rm.z);
        LR[j*4+3][k1l] = sc * (rs.w + rm.w);
        LI[j*4+0][k1l] = sc * (is.x - im.x);
        LI[j*4+1][k1l] = sc * (is.y - im.y);
        LI[j*4+2][k1l] = sc * (is.z - im.z);
        LI[j*4+3][k1l] = sc * (is.w - im.w);
    }
    __syncthreads();
    const size_t ob = (size_t)k2 * 512 + k1g;
    #pragma unroll
    for (int t = 0; t < 4; t++) {
        int idx = tid + t * 256;
        int io = idx >> 4, fq = idx & 15;
        float4 vr = make_float4(LR[io][fq*4], LR[io][fq*4+1], LR[io][fq*4+2], LR[io][fq*4+3]);
        float4 vi = make_float4(LI[io][fq*4], LI[io][fq*4+1], LI[io][fq*4+2], LI[io][fq*4+3]);
        *(float4*)(KeR + (size_t)io * 131072 + ob + fq * 4) = vr;
        *(float4*)(KeI + (size_t)io * 131072 + ob + fq * 4) = vi;
    }
}

// ---------------------------------------------------------------------------
// Split-f16 MFMA GEMM v3. Block (2*WM)x(2*WN), 4 waves 2x2, wave WMxWN.
// NPD: data planes (4 complex / 2 real). TBA: table is A (data is B).
// DREAL: fp32 Re-only output.
// ---------------------------------------------------------------------------
template<int NPD, bool TBA, bool DREAL, int WM, int WN>
__global__ __launch_bounds__(TPB, 2)
void mgemm_k(int K, const _Float16* __restrict__ Tf,
             const _Float16* __restrict__ Dd, long sDz,
             _Float16* __restrict__ Out, long sOz, int OutKc,
             float* __restrict__ Of, long sOfz, int OfN)
{
    constexpr int MT = WM / 32, NT = WN / 32;
    constexpr int TT = TBA ? MT : NT;         // table tiles per wave
    constexpr int DT = TBA ? NT : MT;         // data tiles per wave
    constexpr int SLOTS = NPD * 2;            // 16B slots per col per step
    constexpr int DE  = TBA ? 2 * WN : 2 * WM; // data-side extent in block
    constexpr int CPT = DE * SLOTS / TPB;     // staged chunks per thread
    constexpr int BUF = DE * SLOTS * 8;       // halfs per LDS buffer
    __shared__ _Float16 sm[2 * BUF];

    const int tid = threadIdx.x;
    const int bm = blockIdx.y * (2 * WM), bn = blockIdx.x * (2 * WN);
    const int z = blockIdx.z;
    const _Float16* D = Dd + (size_t)z * sDz;

    const int l  = tid & 63;
    const int wv = tid >> 6;
    const int lr = l & 31, lg = l >> 5;
    const int wm = (wv >> 1) * WM, wn = (wv & 1) * WN;
    const int Kc16 = K >> 4;

    // table-side per-thread fragment pointers (advance 2048 halfs per k-step)
    const int tb = (TBA ? bm + wm : bn + wn);
    const _Float16* tP[TT];
    #pragma unroll
    for (int tt = 0; tt < TT; tt++)
        tP[tt] = Tf + (size_t)(((tb + tt * 32) >> 5) * Kc16) * 2048 + l * 8;

    // data-side fragment LDS offsets
    const int db = (TBA ? wn : wm);
    int dOff[DT][NPD];
    #pragma unroll
    for (int t = 0; t < DT; t++) {
        int cl = db + t * 32 + lr;
        int sw = cl & (SLOTS - 1);
        #pragma unroll
        for (int p = 0; p < NPD; p++)
            dOff[t][p] = cl * (NPD * 16) + (((p * 2 + lg) ^ sw) * 8);
    }

    // staging descriptors
    const int bSide = (TBA ? bn : bm);
    const _Float16* gP[CPT];
    int lO[CPT];
    #pragma unroll
    for (int j = 0; j < CPT; j++) {
        int cid = tid + j * TPB;
        int col = cid / SLOTS;
        int inner = cid & (SLOTS - 1);
        int p = inner & (NPD - 1);
        int h = inner / NPD;
        gP[j] = D + ((size_t)(bSide + col) * (K >> 3) + h) * (NPD * 8) + p * 8;
        lO[j] = col * (NPD * 16) + (((p * 2 + h) ^ (col & (SLOTS - 1))) * 8);
    }

    floatx16 accR[MT][NT], accI[MT][NT];
    #pragma unroll
    for (int i = 0; i < MT; i++)
        #pragma unroll
        for (int j = 0; j < NT; j++)
            #pragma unroll
            for (int r = 0; r < 16; r++) { accR[i][j][r] = 0.f; accI[i][j][r] = 0.f; }

    // prologue: stage step-0 data to LDS, prefetch step-1 data, load table 0
    uintx4 st[CPT];
    #pragma unroll
    for (int j = 0; j < CPT; j++) { st[j] = *(const uintx4*)gP[j]; gP[j] += NPD * 16; }
    #pragma unroll
    for (int j = 0; j < CPT; j++) *(uintx4*)(sm + lO[j]) = st[j];
    #pragma unroll
    for (int j = 0; j < CPT; j++) { st[j] = *(const uintx4*)gP[j]; gP[j] += NPD * 16; }
    half8 tf[TT][4];
    #pragma unroll
    for (int tt = 0; tt < TT; tt++) {
        #pragma unroll
        for (int p = 0; p < 4; p++) tf[tt][p] = *(const half8*)(tP[tt] + p * 512);
        tP[tt] += 2048;
    }
    __syncthreads();

    const int NTs = K >> 4;
    int cur = 0;
    for (int t = 0; t < NTs; t++) {
        const _Float16* smc = sm + cur * BUF;

        // negated table imag planes (complex-table variants)
        half8 na[TT][2];
        if constexpr (TBA && NPD == 4 && !DREAL) {
            #pragma unroll
            for (int tt = 0; tt < TT; tt++) {
                na[tt][0] = neg8(tf[tt][2]);
                na[tt][1] = neg8(tf[tt][3]);
            }
        }

        // MFMA phase, blocked over data tiles (df live = NPD half8 regs)
        #pragma unroll
        for (int dt = 0; dt < DT; dt++) {
            half8 dfl[NPD];
            #pragma unroll
            for (int p = 0; p < NPD; p++)
                dfl[p] = *(const half8*)(smc + dOff[dt][p]);

            if constexpr (TBA && NPD == 4 && !DREAL) {
                // complex x complex: A = table, B = data (S2/S4); nt = dt
                #pragma unroll
                for (int mt = 0; mt < MT; mt++) {
                    accR[mt][dt] = __builtin_amdgcn_mfma_f32_32x32x16_f16(tf[mt][0], dfl[0], accR[mt][dt], 0,0,0);
                    accR[mt][dt] = __builtin_amdgcn_mfma_f32_32x32x16_f16(tf[mt][0], dfl[1], accR[mt][dt], 0,0,0);
                    accR[mt][dt] = __builtin_amdgcn_mfma_f32_32x32x16_f16(tf[mt][1], dfl[0], accR[mt][dt], 0,0,0);
                    accR[mt][dt] = __builtin_amdgcn_mfma_f32_32x32x16_f16(na[mt][0], dfl[2], accR[mt][dt], 0,0,0);
                    accR[mt][dt] = __builtin_amdgcn_mfma_f32_32x32x16_f16(na[mt][0], dfl[3], accR[mt][dt], 0,0,0);
                    accR[mt][dt] = __builtin_amdgcn_mfma_f32_32x32x16_f16(na[mt][1], dfl[2], accR[mt][dt], 0,0,0);
                    accI[mt][dt] = __builtin_amdgcn_mfma_f32_32x32x16_f16(tf[mt][0], dfl[2], accI[mt][dt], 0,0,0);
                    accI[mt][dt] = __builtin_amdgcn_mfma_f32_32x32x16_f16(tf[mt][0], dfl[3], accI[mt][dt], 0,0,0);
                    accI[mt][dt] = __builtin_amdgcn_mfma_f32_32x32x16_f16(tf[mt][1], dfl[2], accI[mt][dt], 0,0,0);
                    accI[mt][dt] = __builtin_amdgcn_mfma_f32_32x32x16_f16(tf[mt][2], dfl[0], accI[mt][dt], 0,0,0);
                    accI[mt][dt] = __builtin_amdgcn_mfma_f32_32x32x16_f16(tf[mt][2], dfl[1], accI[mt][dt], 0,0,0);
                    accI[mt][dt] = __builtin_amdgcn_mfma_f32_32x32x16_f16(tf[mt][3], dfl[0], accI[mt][dt], 0,0,0);
                }
            } else if constexpr (TBA && NPD == 2) {
                // S1: complex table x real data; nt = dt
                #pragma unroll
                for (int mt = 0; mt < MT; mt++) {
                    accR[mt][dt] = __builtin_amdgcn_mfma_f32_32x32x16_f16(tf[mt][0], dfl[0], accR[mt][dt], 0,0,0);
                    accR[mt][dt] = __builtin_amdgcn_mfma_f32_32x32x16_f16(tf[mt][0], dfl[1], accR[mt][dt], 0,0,0);
                    accR[mt][dt] = __builtin_amdgcn_mfma_f32_32x32x16_f16(tf[mt][1], dfl[0], accR[mt][dt], 0,0,0);
                    accI[mt][dt] = __builtin_amdgcn_mfma_f32_32x32x16_f16(tf[mt][2], dfl[0], accI[mt][dt], 0,0,0);
                    accI[mt][dt] = __builtin_amdgcn_mfma_f32_32x32x16_f16(tf[mt][2], dfl[1], accI[mt][dt], 0,0,0);
                    accI[mt][dt] = __builtin_amdgcn_mfma_f32_32x32x16_f16(tf[mt][3], dfl[0], accI[mt][dt], 0,0,0);
                }
            } else {
                // S5: A = data (LDS complex), B = table, Re-only; mt = dt
                half8 nd0 = neg8(dfl[2]);
                half8 nd1 = neg8(dfl[3]);
                #pragma unroll
                for (int nt = 0; nt < NT; nt++) {
                    accR[dt][nt] = __builtin_amdgcn_mfma_f32_32x32x16_f16(dfl[0], tf[nt][0], accR[dt][nt], 0,0,0);
                    accR[dt][nt] = __builtin_amdgcn_mfma_f32_32x32x16_f16(dfl[0], tf[nt][1], accR[dt][nt], 0,0,0);
                    accR[dt][nt] = __builtin_amdgcn_mfma_f32_32x32x16_f16(dfl[1], tf[nt][0], accR[dt][nt], 0,0,0);
                    accR[dt][nt] = __builtin_amdgcn_mfma_f32_32x32x16_f16(nd0, tf[nt][2], accR[dt][nt], 0,0,0);
                    accR[dt][nt] = __builtin_amdgcn_mfma_f32_32x32x16_f16(nd0, tf[nt][3], accR[dt][nt], 0,0,0);
                    accR[dt][nt] = __builtin_amdgcn_mfma_f32_32x32x16_f16(nd1, tf[nt][2], accR[dt][nt], 0,0,0);
                }
            }
        }

        // next-step preparations (independent of MFMA above); the barrier's
        // vmcnt drain guarantees the reloaded tf/st are ready next iteration.
        if (t + 1 < NTs) {
            _Float16* smn = sm + (cur ^ 1) * BUF;
            #pragma unroll
            for (int j = 0; j < CPT; j++) *(uintx4*)(smn + lO[j]) = st[j];
            #pragma unroll
            for (int tt = 0; tt < TT; tt++) {
                #pragma unroll
                for (int p = 0; p < 4; p++) tf[tt][p] = *(const half8*)(tP[tt] + p * 512);
                tP[tt] += 2048;
            }
            if (t + 2 < NTs) {
                #pragma unroll
                for (int j = 0; j < CPT; j++) { st[j] = *(const uintx4*)gP[j]; gP[j] += NPD * 16; }
            }
        }
        __syncthreads();
        cur ^= 1;
    }

    // epilogue: C/D layout col = lane&31, row = (r&3) + 8*(r>>2) + 4*lg
    if constexpr (DREAL) {
        float* Dv = Of + (size_t)z * sOfz;
        #pragma unroll
        for (int mt = 0; mt < MT; mt++)
            #pragma unroll
            for (int nt = 0; nt < NT; nt++)
                #pragma unroll
                for (int r = 0; r < 16; r++) {
                    int row = bm + wm + mt * 32 + (r & 3) + 8 * (r >> 2) + 4 * lg;
                    int col = bn + wn + nt * 32 + lr;
                    Dv[(size_t)row * OfN + col] = accR[mt][nt][r];
                }
    } else {
        _Float16* O = Out + (size_t)z * sOz;
        #pragma unroll
        for (int mt = 0; mt < MT; mt++)
            #pragma unroll
            for (int nt = 0; nt < NT; nt++)
                #pragma unroll
                for (int r = 0; r < 16; r++) {
                    int row = bm + wm + mt * 32 + (r & 3) + 8 * (r >> 2) + 4 * lg;
                    int col = bn + wn + nt * 32 + lr;
                    size_t base = ((size_t)row * OutKc + (col >> 3)) * 32 + (col & 7);
                    _Float16 h, lo;
                    split16(accR[mt][nt][r], h, lo);
                    O[base]      = h;
                    O[base + 8]  = lo;
                    split16(accI[mt][nt][r], h, lo);
                    O[base + 16] = h;
                    O[base + 24] = lo;
                }
    }
}

// ---------------------------------------------------------------------------
// Channel mix on F2T (interleaved layout), image-tiled by 4 to reuse Ke.
// ---------------------------------------------------------------------------
__global__ __launch_bounds__(TPB)
void einsum_k(_Float16* __restrict__ F, const float* __restrict__ KeR,
              const float* __restrict__ KeI, int g)
{
    const int pt = blockIdx.x * TPB + threadIdx.x;   // k2*512 + k1
    const int k2 = pt >> 9, k1 = pt & 511;
    const size_t fo = ((size_t)(k2 * 64 + (k1 >> 3))) * 32 + (k1 & 7);

    for (int b0 = 0; b0 < g; b0 += 4) {
        const int bt = (g - b0 < 4) ? (g - b0) : 4;
        float xr[4][8], xi[4][8];
        #pragma unroll
        for (int bb = 0; bb < 4; bb++) {
            if (bb >= bt) break;
            #pragma unroll
            for (int i = 0; i < 8; i++) {
                const _Float16* P = F + ((size_t)((b0 + bb) * 8 + i)) * 524288 + fo;
                xr[bb][i] = (float)P[0]  + (float)P[8];
                xi[bb][i] = (float)P[16] + (float)P[24];
            }
        }
        #pragma unroll
        for (int o = 0; o < 8; o++) {
            float ar[4] = {0.f,0.f,0.f,0.f}, ai[4] = {0.f,0.f,0.f,0.f};
            #pragma unroll
            for (int i = 0; i < 8; i++) {
                float kr = KeR[(size_t)(i * 8 + o) * 131072 + pt];
                float ki = KeI[(size_t)(i * 8 + o) * 131072 + pt];
                #pragma unroll
                for (int bb = 0; bb < 4; bb++) {
                    ar[bb] = fmaf(xr[bb][i], kr, ar[bb]);
                    ar[bb] = fmaf(-xi[bb][i], ki, ar[bb]);
                    ai[bb] = fmaf(xr[bb][i], ki, ai[bb]);
                    ai[bb] = fmaf(xi[bb][i], kr, ai[bb]);
                }
            }
            #pragma unroll
            for (int bb = 0; bb < 4; bb++) {
                if (bb >= bt) break;
                _Float16* Q = F + ((size_t)((b0 + bb) * 8 + o)) * 524288 + fo;
                _Float16 h, lo;
                split16(ar[bb], h, lo); Q[0]  = h; Q[8]  = lo;
                split16(ai[bb], h, lo); Q[16] = h; Q[24] = lo;
            }
        }
    }
}

// ---------------------------------------------------------------------------
// out[b][p][q][o] = Dq[(bl*8+o)][p*256+q] / 511^2 + bias[o]
// ---------------------------------------------------------------------------
__global__ __launch_bounds__(TPB)
void tout_k(const float* __restrict__ Dq, const float* __restrict__ bias,
            float* __restrict__ out, int b0)
{
    int idx = blockIdx.x * TPB + threadIdx.x;
    int o = idx & 7, q = (idx >> 3) & 255, p = (idx >> 11) & 255, bl = idx >> 19;
    float v = Dq[(size_t)(bl * 8 + o) * 65536 + p * 256 + q];
    out[(size_t)(b0 + bl) * 524288 + (size_t)(idx & 524287)] = v * (1.f / 261121.f) + bias[o];
}

// ---------------------------------------------------------------------------

extern "C" void kernel_launch(void* const* d_in, const int* in_sizes, int n_in,
                              void* d_out, int out_size, void* d_ws, size_t ws_size,
                              hipStream_t stream) {
    const float* x    = (const float*)d_in[0];
    const float* Kr   = (const float*)d_in[1];
    const float* Ki   = Kr + 16711744;          // 511*511*64
    const float* bias = (const float*)d_in[2];
    float* out = (float*)d_out;
    char* ws = (char*)d_ws;

    _Float16* AtabF = (_Float16*)(ws + 0);           //  1,048,576
    _Float16* CtabF = (_Float16*)(ws + 1048576);     //  1,048,576
    _Float16* Ct2F  = (_Float16*)(ws + 2097152);     //    524,288
    _Float16* xTp   = (_Float16*)(ws + 2621440);     // 16,777,216
    float*    KeR   = (float*)   (ws + 19398656);    // 33,554,432
    float*    KeI   = (float*)   (ws + 52953088);    // 33,554,432
    const size_t fixedEnd = 86507520;

    int g = 1;
    for (int cand = 8; cand >= 1; cand >>= 1) {
        if (fixedEnd + (size_t)cand * 16777216 <= ws_size) { g = cand; break; }
    }
    _Float16* F1  = (_Float16*)(ws + fixedEnd);                        // g*8 MB
    _Float16* F2T = (_Float16*)(ws + fixedEnd + (size_t)g * 8388608);  // g*8 MB
    _Float16* F1b = F1;                 // alias: F1 dead after S2
    float*    Dq  = (float*)F2T;        // alias: F2T dead after S4

    build_tables_k<<<160, TPB, 0, stream>>>(AtabF, CtabF, Ct2F);
    txp_k<<<dim3(8, 8, 8), TPB, 0, stream>>>(x, xTp);
    ksym_k<<<2048, TPB, 0, stream>>>(Kr, Ki, KeR, KeI);

    for (int b0 = 0; b0 < 8; b0 += g) {
        int Z = g * 8;
        // S1: F1[k1][w] (M=512,N=256,K=256), A=Atab, B=xTp (real), 128x128
        mgemm_k<2, true, false, 64, 64><<<dim3(2, 4, Z), TPB, 0, stream>>>(
            256, AtabF,
            xTp + (size_t)b0 * 8 * 131072, 131072,
            F1, 524288, 32, nullptr, 0, 0);

        // S2: F2T[k2][k1] (M=256,N=512,K=256), A=Atab(rows 0..255), B=F1, 128x128
        mgemm_k<4, true, false, 64, 64><<<dim3(4, 2, Z), TPB, 0, stream>>>(
            256, AtabF,
            F1, 524288,
            F2T, 524288, 64, nullptr, 0, 0);

        // S3: channel mix
        einsum_k<<<512, TPB, 0, stream>>>(F2T, KeR, KeI, g);

        // S4: F1'[p][k2] (M=256,N=256,K=512), A=Ctab, B=F2T, 64x128
        mgemm_k<4, true, false, 32, 64><<<dim3(2, 4, Z), TPB, 0, stream>>>(
            512, CtabF,
            F2T, 524288,
            F1b, 262144, 32, nullptr, 0, 0);

        // S5: Dq[p][q] (M=256,N=256,K=256), A=F1' (data), B=Ct2 table, 128x64
        mgemm_k<4, false, true, 64, 32><<<dim3(4, 2, Z), TPB, 0, stream>>>(
            256, Ct2F,
            F1b, 262144,
            nullptr, 0, 0, Dq, 65536, 256);

        // S6: transpose to NHWC + scale + bias
        tout_k<<<g * 2048, TPB, 0, stream>>>(Dq, bias, out, b0);
    }
}